// Round 2
// baseline (310.391 us; speedup 1.0000x reference)
//
#include <hip/hip_runtime.h>
#include <stdint.h>

#define BATCH 4
#define SEQ   1024
#define NHEAD 16
#define DHEAD 128
#define HDIM  2048
#define GM    4096   /* BATCH*SEQ */
#define GK    2048
#define NT    32     /* GK/64 K-tiles */

typedef __attribute__((ext_vector_type(8))) short short8;
typedef __attribute__((ext_vector_type(4))) float f32x4;

__device__ __forceinline__ uint16_t f2bf(float f) {
  uint32_t u = __builtin_bit_cast(uint32_t, f);
  u += 0x7fffu + ((u >> 16) & 1u);
  return (uint16_t)(u >> 16);
}
__device__ __forceinline__ float bf2f(uint16_t h) {
  return __builtin_bit_cast(float, (uint32_t)h << 16);
}

// XOR swizzles (involutions) for rowlen-128B and -256B LDS tiles
__device__ __forceinline__ uint32_t swz128(uint32_t a) { return a ^ (((a >> 7) & 7u) << 4); }
__device__ __forceinline__ uint32_t swz256(uint32_t a) { return a ^ (((a >> 8) & 7u) << 4); }

#define GAS __attribute__((address_space(1)))
#define LAS __attribute__((address_space(3)))
__device__ __forceinline__ void gload_lds16(const void* g, void* l) {
  // LDS dest = wave-uniform base (HW adds lane*16); global src is per-lane.
  __builtin_amdgcn_global_load_lds((GAS const void*)g, (LAS void*)l, 16, 0, 0);
}

#define SBAR  do { __builtin_amdgcn_s_barrier(); __builtin_amdgcn_sched_barrier(0); } while (0)
#define LGKM0 do { asm volatile("s_waitcnt lgkmcnt(0)" ::: "memory"); __builtin_amdgcn_sched_barrier(0); } while (0)
#define VM4   do { asm volatile("s_waitcnt vmcnt(4)" ::: "memory"); __builtin_amdgcn_sched_barrier(0); } while (0)

// ---------------- fp32 -> bf16 converts ----------------
__global__ void cvt_kernel(const float* __restrict__ in, uint16_t* __restrict__ out, int n8) {
  int i = blockIdx.x * 256 + threadIdx.x;
  if (i >= n8) return;
  const float4* p = (const float4*)in + (size_t)i * 2;
  float4 a = p[0], b = p[1];
  uint32_t w0 = f2bf(a.x) | ((uint32_t)f2bf(a.y) << 16);
  uint32_t w1 = f2bf(a.z) | ((uint32_t)f2bf(a.w) << 16);
  uint32_t w2 = f2bf(b.x) | ((uint32_t)f2bf(b.y) << 16);
  uint32_t w3 = f2bf(b.z) | ((uint32_t)f2bf(b.w) << 16);
  int4 r; r.x = (int)w0; r.y = (int)w1; r.z = (int)w2; r.w = (int)w3;
  *(int4*)(out + (size_t)i * 8) = r;
}

__global__ void cvtw_kernel(const float* __restrict__ W0, const float* __restrict__ W1,
                            const float* __restrict__ W2, const float* __restrict__ W3,
                            uint16_t* __restrict__ out) {
  const float* src = (blockIdx.y == 0) ? W0 : (blockIdx.y == 1) ? W1 : (blockIdx.y == 2) ? W2 : W3;
  int i = blockIdx.x * 256 + threadIdx.x;  // 8-elem group, 524288 per matrix
  const float4* p = (const float4*)src + (size_t)i * 2;
  float4 a = p[0], b = p[1];
  uint32_t w0 = f2bf(a.x) | ((uint32_t)f2bf(a.y) << 16);
  uint32_t w1 = f2bf(a.z) | ((uint32_t)f2bf(a.w) << 16);
  uint32_t w2 = f2bf(b.x) | ((uint32_t)f2bf(b.y) << 16);
  uint32_t w3 = f2bf(b.z) | ((uint32_t)f2bf(b.w) << 16);
  int4 r; r.x = (int)w0; r.y = (int)w1; r.z = (int)w2; r.w = (int)w3;
  *(int4*)(out + (size_t)blockIdx.y * HDIM * HDIM + (size_t)i * 8) = r;
}

// ---------------- 8-phase GEMM: C = A(MxK) @ W(NxK)^T + bias ----------------
// BM=256 BN=128 BK=64, 512 thr = 8 waves (4M x 2N), per-wave 64x64 (acc[4][4]).
// LDS 96KB: A[2][256][64] + B[2][128][64] bf16, swz128 within 128B rows.
// Schedule per K-tile t (4 phases): reads front-loaded (A all at p1, B at p1/p2);
// stages: p1 B(t+1)h0, p2 B(t+1)h1, p3 A(t+2)h0, p4 A(t+2)h1; vmcnt(4) at p4 only.
// MODE 0: bf16 out, rope when blockIdx.z<2 (q,k).  MODE 1: f32 out.
template <int MODE>
__global__ __launch_bounds__(512, 2) void gemm8_kernel(
    const uint16_t* __restrict__ A,
    const uint16_t* __restrict__ W0, const uint16_t* __restrict__ W1, const uint16_t* __restrict__ W2,
    const float* __restrict__ b0, const float* __restrict__ b1, const float* __restrict__ b2,
    const float* __restrict__ fcos, const float* __restrict__ fsin,
    void* __restrict__ o0, void* __restrict__ o1, void* __restrict__ o2) {
  __shared__ __align__(16) char ldsA[65536];
  __shared__ __align__(16) char ldsB[32768];
  const int tid = threadIdx.x, lane = tid & 63, wid = tid >> 6;
  const int c = lane & 15, g = lane >> 4;
  const int wr = wid >> 1, wc = wid & 1;
  const int row0 = blockIdx.x * 256, col0 = blockIdx.y * 128;
  const uint16_t* W = (blockIdx.z == 0) ? W0 : (blockIdx.z == 1) ? W1 : W2;
  const float* bias = (blockIdx.z == 0) ? b0 : (blockIdx.z == 1) ? b1 : b2;

  // staging address components (wid drops out of the swizzled column)
  const uint32_t colswz = ((uint32_t)((lane & 7) ^ (lane >> 3))) << 4;
  const int sr = wid * 8 + (lane >> 3);

  auto stageA = [&](int t, int half) {
    int ts = (t < NT) ? t : 0;
    int buf = t & 1;
    const char* s0 = (const char*)A + (size_t)(row0 + half * 128 + sr) * (GK * 2) + ts * 128 + colswz;
    char* d = ldsA + buf * 32768 + half * 16384 + wid * 1024;
    gload_lds16(s0, d);
    gload_lds16(s0 + (size_t)64 * (GK * 2), d + 8192);
  };
  auto stageB = [&](int t, int half) {
    int ts = (t < NT) ? t : 0;
    int buf = t & 1;
    gload_lds16((const char*)W + (size_t)(col0 + half * 64 + sr) * (GK * 2) + ts * 128 + colswz,
                ldsB + buf * 16384 + half * 8192 + wid * 1024);
  };
  auto ldA = [&](const char* sA, int row, int ks) -> short8 {
    uint32_t a = (uint32_t)((row & 127) * 128) + (((uint32_t)(ks * 64 + g * 16)) ^ (((uint32_t)row & 7u) << 4));
    return *(const short8*)(sA + (row >> 7) * 16384 + a);
  };
  auto ldB = [&](const char* sB, int crow, int ks) -> short8 {
    uint32_t a = (uint32_t)((crow & 63) * 128) + (((uint32_t)(ks * 64 + g * 16)) ^ (((uint32_t)crow & 7u) << 4));
    return *(const short8*)(sB + (crow >> 6) * 8192 + a);
  };

  f32x4 acc[4][4] = {};

  // prologue: tile0 A+B, tile1 A; leave tile1-A's 4 loads in flight
  stageA(0, 0); stageA(0, 1); stageB(0, 0); stageB(0, 1); stageA(1, 0); stageA(1, 1);
  VM4; SBAR;

  for (int t = 0; t < NT; ++t) {
    const char* sA = ldsA + (t & 1) * 32768;
    const char* sB = ldsB + (t & 1) * 16384;
    short8 af[4][2], bA[2][2], bB[2][2];
    // ---- phase 1: read all A frags + B qn0; stage B(t+1)h0; MFMA quad(0,0)
#pragma unroll
    for (int mi = 0; mi < 4; ++mi)
#pragma unroll
      for (int ks = 0; ks < 2; ++ks) af[mi][ks] = ldA(sA, wr * 64 + mi * 16 + c, ks);
#pragma unroll
    for (int nj = 0; nj < 2; ++nj)
#pragma unroll
      for (int ks = 0; ks < 2; ++ks) bA[nj][ks] = ldB(sB, wc * 64 + nj * 16 + c, ks);
    stageB(t + 1, 0);
    SBAR;
    __builtin_amdgcn_s_setprio(1);
#pragma unroll
    for (int mi = 0; mi < 2; ++mi)
#pragma unroll
      for (int nj = 0; nj < 2; ++nj)
#pragma unroll
        for (int ks = 0; ks < 2; ++ks)
          acc[mi][nj] = __builtin_amdgcn_mfma_f32_16x16x32_bf16(af[mi][ks], bA[nj][ks], acc[mi][nj], 0, 0, 0);
    __builtin_amdgcn_s_setprio(0);
    LGKM0;  // af[2..3] reads must land before p3 overwrites buf(t).A
    SBAR;
    // ---- phase 2: read B qn1; stage B(t+1)h1; MFMA quad(0,1)
#pragma unroll
    for (int nj = 0; nj < 2; ++nj)
#pragma unroll
      for (int ks = 0; ks < 2; ++ks) bB[nj][ks] = ldB(sB, wc * 64 + (2 + nj) * 16 + c, ks);
    stageB(t + 1, 1);
    SBAR;
    __builtin_amdgcn_s_setprio(1);
#pragma unroll
    for (int mi = 0; mi < 2; ++mi)
#pragma unroll
      for (int nj = 0; nj < 2; ++nj)
#pragma unroll
        for (int ks = 0; ks < 2; ++ks)
          acc[mi][2 + nj] = __builtin_amdgcn_mfma_f32_16x16x32_bf16(af[mi][ks], bB[nj][ks], acc[mi][2 + nj], 0, 0, 0);
    __builtin_amdgcn_s_setprio(0);
    SBAR;
    // ---- phase 3: stage A(t+2)h0 into buf(t) (A reads done since p1); MFMA quad(1,0)
    stageA(t + 2, 0);
    SBAR;
    __builtin_amdgcn_s_setprio(1);
#pragma unroll
    for (int mi = 0; mi < 2; ++mi)
#pragma unroll
      for (int nj = 0; nj < 2; ++nj)
#pragma unroll
        for (int ks = 0; ks < 2; ++ks)
          acc[2 + mi][nj] = __builtin_amdgcn_mfma_f32_16x16x32_bf16(af[2 + mi][ks], bA[nj][ks], acc[2 + mi][nj], 0, 0, 0);
    __builtin_amdgcn_s_setprio(0);
    SBAR;
    // ---- phase 4: stage A(t+2)h1; MFMA quad(1,1); counted vmcnt (never 0)
    stageA(t + 2, 1);
    SBAR;
    __builtin_amdgcn_s_setprio(1);
#pragma unroll
    for (int mi = 0; mi < 2; ++mi)
#pragma unroll
      for (int nj = 0; nj < 2; ++nj)
#pragma unroll
        for (int ks = 0; ks < 2; ++ks)
          acc[2 + mi][2 + nj] = __builtin_amdgcn_mfma_f32_16x16x32_bf16(af[2 + mi][ks], bB[nj][ks], acc[2 + mi][2 + nj], 0, 0, 0);
    __builtin_amdgcn_s_setprio(0);
    VM4;  // tile t+1's 4 half-tiles arrived; only A(t+2) stays in flight
    SBAR;
  }

  // ---- epilogue: bias (+ rope for q/k) ----
  void* outp = (blockIdx.z == 0) ? o0 : (blockIdx.z == 1) ? o1 : o2;
  const bool dorope = (MODE == 0) && (blockIdx.z < 2);
  float bn[4];
#pragma unroll
  for (int nj = 0; nj < 4; ++nj) bn[nj] = bias[col0 + wc * 64 + nj * 16 + c];
#pragma unroll
  for (int mi = 0; mi < 4; ++mi) {
#pragma unroll
    for (int jj = 0; jj < 4; ++jj) {
      const int row = row0 + wr * 64 + mi * 16 + g * 4 + jj;
      const int s = row & (SEQ - 1);
#pragma unroll
      for (int nj = 0; nj < 4; ++nj) {
        const int d = wc * 64 + nj * 16 + c;   // col within 128-tile; col0%128==0 -> d == col%DHEAD
        float v = acc[mi][nj][jj] + bn[nj];
        float res = v;
        if (dorope) {
          float cs = fcos[s * 64 + (d >> 1)];
          float sn = fsin[s * 64 + (d >> 1)];
          float o = __shfl_xor(v, 1, 64);
          res = (c & 1) ? (o * sn + v * cs) : (v * cs - o * sn);
        }
        const size_t idx = (size_t)row * HDIM + col0 + d;
        if (MODE == 1) ((float*)outp)[idx] = res;
        else           ((uint16_t*)outp)[idx] = f2bf(res);
      }
    }
  }
}

// ---------------- flash attention (unchanged from round 1) ----------------
__global__ __launch_bounds__(256, 2) void attn_kernel(
    const uint16_t* __restrict__ q, const uint16_t* __restrict__ k,
    const uint16_t* __restrict__ v, const float* __restrict__ mask,
    uint16_t* __restrict__ ctx) {
  __shared__ __align__(16) char smQ[64 * 256];
  __shared__ __align__(16) char smK[64 * 256];
  __shared__ __align__(16) char smVT[128 * 128];
  __shared__ __align__(16) char smP[64 * 128];
  __shared__ float smMask[64];
  __shared__ float smScale[64];

  const int tid = threadIdx.x, lane = tid & 63, wid = tid >> 6;
  const int c = lane & 15, g = lane >> 4;
  const int b = blockIdx.z, h = blockIdx.y, q0 = blockIdx.x * 64;
  const float scale = 0.022097086912079608f;  // 1/sqrt(2048)

#pragma unroll
  for (int i = 0; i < 4; ++i) {
    uint32_t o = wid * 4096 + i * 1024 + lane * 16;
    uint32_t r = o >> 8;
    uint32_t cb = swz256(o) & 255;
    gload_lds16((const char*)q + ((size_t)(b * SEQ + q0 + r) * HDIM + h * DHEAD) * 2 + cb,
                smQ + wid * 4096 + i * 1024);
  }

  float mreg = -1e30f, lreg = 0.f;
  f32x4 oacc[8] = {};

  for (int t = 0; t < 16; ++t) {
    const int kv0 = t * 64;
    __syncthreads();
#pragma unroll
    for (int i = 0; i < 4; ++i) {
      uint32_t o = wid * 4096 + i * 1024 + lane * 16;
      uint32_t r = o >> 8;
      uint32_t cb = swz256(o) & 255;
      gload_lds16((const char*)k + ((size_t)(b * SEQ + kv0 + r) * HDIM + h * DHEAD) * 2 + cb,
                  smK + wid * 4096 + i * 1024);
    }
    if (tid < 64) smMask[tid] = mask[b * SEQ + kv0 + tid];
    {
      const int kvr = tid >> 2, dblk = tid & 3;
      const uint16_t* src = v + (size_t)(b * SEQ + kv0 + kvr) * HDIM + h * DHEAD + dblk * 32;
      uint16_t tmp[32];
      *(int4*)(tmp)      = *(const int4*)(src);
      *(int4*)(tmp + 8)  = *(const int4*)(src + 8);
      *(int4*)(tmp + 16) = *(const int4*)(src + 16);
      *(int4*)(tmp + 24) = *(const int4*)(src + 24);
#pragma unroll
      for (int e = 0; e < 32; ++e) {
        int d = dblk * 32 + e;
        *(uint16_t*)(smVT + swz128((uint32_t)(d * 128 + kvr * 2))) = tmp[e];
      }
    }
    __syncthreads();

    f32x4 st[4] = {};
#pragma unroll
    for (int ks = 0; ks < 4; ++ks) {
      short8 qf = *(const short8*)(smQ + swz256((uint32_t)((wid * 16 + c) * 256 + ks * 64 + g * 16)));
#pragma unroll
      for (int mi = 0; mi < 4; ++mi) {
        short8 kf = *(const short8*)(smK + swz256((uint32_t)((mi * 16 + c) * 256 + ks * 64 + g * 16)));
        st[mi] = __builtin_amdgcn_mfma_f32_16x16x32_bf16(kf, qf, st[mi], 0, 0, 0);
      }
    }
    float sv[4][4];
    float pmax = -1e30f;
#pragma unroll
    for (int mi = 0; mi < 4; ++mi) {
      float4 mb = *(const float4*)(smMask + mi * 16 + g * 4);
      float mbv[4] = {mb.x, mb.y, mb.z, mb.w};
#pragma unroll
      for (int jj = 0; jj < 4; ++jj) {
        float s = st[mi][jj] * scale;
        if (mbv[jj] == 0.f) s = -1e9f;
        sv[mi][jj] = s;
        pmax = fmaxf(pmax, s);
      }
    }
    pmax = fmaxf(pmax, __shfl_xor(pmax, 16, 64));
    pmax = fmaxf(pmax, __shfl_xor(pmax, 32, 64));
    float mnew = fmaxf(mreg, pmax);
    float fac = __expf(mreg - mnew);
    float rsum = 0.f;
    uint32_t pw[4][2];
#pragma unroll
    for (int mi = 0; mi < 4; ++mi) {
      float p0 = __expf(sv[mi][0] - mnew);
      float p1 = __expf(sv[mi][1] - mnew);
      float p2 = __expf(sv[mi][2] - mnew);
      float p3 = __expf(sv[mi][3] - mnew);
      rsum += (p0 + p1) + (p2 + p3);
      pw[mi][0] = f2bf(p0) | ((uint32_t)f2bf(p1) << 16);
      pw[mi][1] = f2bf(p2) | ((uint32_t)f2bf(p3) << 16);
    }
    rsum += __shfl_xor(rsum, 16, 64);
    rsum += __shfl_xor(rsum, 32, 64);
    lreg = lreg * fac + rsum;
    mreg = mnew;
#pragma unroll
    for (int mi = 0; mi < 4; ++mi) {
      uint32_t addr = swz128((uint32_t)((wid * 16 + c) * 128 + (mi * 16 + g * 4) * 2));
      uint2 wv; wv.x = pw[mi][0]; wv.y = pw[mi][1];
      *(uint2*)(smP + addr) = wv;
    }
    if (g == 0) smScale[wid * 16 + c] = fac;
    __syncthreads();

    float4 fv = *(const float4*)(smScale + wid * 16 + g * 4);
    float fvv[4] = {fv.x, fv.y, fv.z, fv.w};
#pragma unroll
    for (int nj = 0; nj < 8; ++nj)
#pragma unroll
      for (int jj = 0; jj < 4; ++jj) oacc[nj][jj] *= fvv[jj];
#pragma unroll
    for (int ks = 0; ks < 2; ++ks) {
      short8 pf = *(const short8*)(smP + swz128((uint32_t)((wid * 16 + c) * 128 + ks * 64 + g * 16)));
#pragma unroll
      for (int nj = 0; nj < 8; ++nj) {
        short8 vf = *(const short8*)(smVT + swz128((uint32_t)((nj * 16 + c) * 128 + ks * 64 + g * 16)));
        oacc[nj] = __builtin_amdgcn_mfma_f32_16x16x32_bf16(pf, vf, oacc[nj], 0, 0, 0);
      }
    }
  }

  __syncthreads();
  if (g == 0) smScale[wid * 16 + c] = lreg;
  __syncthreads();
  float4 lv = *(const float4*)(smScale + wid * 16 + g * 4);
  float inv[4] = {1.f / lv.x, 1.f / lv.y, 1.f / lv.z, 1.f / lv.w};
#pragma unroll
  for (int nj = 0; nj < 8; ++nj) {
#pragma unroll
    for (int jj = 0; jj < 4; ++jj) {
      int qrow = q0 + wid * 16 + g * 4 + jj;
      int dcol = h * DHEAD + nj * 16 + c;
      ctx[(size_t)(b * SEQ + qrow) * HDIM + dcol] = f2bf(oacc[nj][jj] * inv[jj]);
    }
  }
}

// ---------------- launch ----------------
extern "C" void kernel_launch(void* const* d_in, const int* in_sizes, int n_in,
                              void* d_out, int out_size, void* d_ws, size_t ws_size,
                              hipStream_t stream) {
  const float* hs   = (const float*)d_in[0];
  const float* fcos = (const float*)d_in[1];
  const float* fsin = (const float*)d_in[2];
  const float* mask = (const float*)d_in[3];
  const float* Wq = (const float*)d_in[4];  const float* bq = (const float*)d_in[5];
  const float* Wk = (const float*)d_in[6];  const float* bk = (const float*)d_in[7];
  const float* Wv = (const float*)d_in[8];  const float* bv = (const float*)d_in[9];
  const float* Wo = (const float*)d_in[10]; const float* bo = (const float*)d_in[11];
  float* out = (float*)d_out;

  char* ws = (char*)d_ws;
  const size_t XB = (size_t)GM * HDIM * 2;    // 16 MB
  const size_t WB = (size_t)HDIM * HDIM * 2;  //  8 MB
  uint16_t* Xbf = (uint16_t*)(ws);            // reused as ctx after QKV
  uint16_t* Wqb = (uint16_t*)(ws + XB);       // Wqb..Wob contiguous (cvtw relies on it)
  uint16_t* Wkb = (uint16_t*)(ws + XB + WB);
  uint16_t* Wvb = (uint16_t*)(ws + XB + 2 * WB);
  uint16_t* Wob = (uint16_t*)(ws + XB + 3 * WB);
  uint16_t* qb  = (uint16_t*)(ws + XB + 4 * WB);
  uint16_t* kb  = (uint16_t*)(ws + XB + 4 * WB + XB);
  uint16_t* vb  = (uint16_t*)(ws + XB + 4 * WB + 2 * XB);

  cvt_kernel<<<4096, 256, 0, stream>>>(hs, Xbf, (GM * HDIM) / 8);
  cvtw_kernel<<<dim3(2048, 4), 256, 0, stream>>>(Wq, Wk, Wv, Wo, Wqb);

  gemm8_kernel<0><<<dim3(GM / 256, HDIM / 128, 3), 512, 0, stream>>>(
      Xbf, Wqb, Wkb, Wvb, bq, bk, bv, fcos, fsin, qb, kb, vb);

  attn_kernel<<<dim3(SEQ / 64, NHEAD, BATCH), 256, 0, stream>>>(qb, kb, vb, mask, Xbf);

  gemm8_kernel<1><<<dim3(GM / 256, HDIM / 128, 1), 512, 0, stream>>>(
      Xbf, Wob, Wob, Wob, bo, bo, bo, fcos, fsin, out, out, out);
}